// Round 1
// 249.344 us; speedup vs baseline: 1.6614x; 1.6614x over previous
//
#include <hip/hip_runtime.h>

#define N_NODES 100000
#define N_EDGES 1600000
#define DIM     64
#define HID     256
#define BN_EPS  1e-5f
#define NGROUPS 1563           // ceil(100000/64) groups of 64 rows
#define MLP_BLOCKS 512

// counting-sort parameters
#define NBUCK   391            // ceil(100000/256) buckets of 256 nodes
#define RSTRIDE 392            // runoff row stride (NBUCK + 1 for chunk total)
#define SCHUNK  8192           // edges per kA_scatter block
#define SBLK    196            // ceil(1600000/8192)
#define MAXB    6144           // max edges per bucket (mean 4096, sigma 64 -> +32 sigma)

typedef short bf16x8 __attribute__((ext_vector_type(8)));
typedef float f32x4  __attribute__((ext_vector_type(4)));

// ws layout (4-byte units):
//   deg        int[100000]        @ 0
//   stats      float[128]         @ 100000   (sum[64], sumsq[64])     [zeroed]
//   ss         float[128]         @ 100128   (scale[64], shift[64])   [zeroed]
//   bucket_cnt int[400]           @ 100256                            [zeroed]
//   bucket_off int[400]           @ 100656
//   offsets    int[100000]        @ 101056
//   runoff     int[196*392]       @ 201056   (76832)
//   w1t_g      bf16[256*64]       @ 277888   (8192 ints)  [n][k]
//   w2t_g      bf16[64*256]       @ 286080   (8192 ints)  [d][k2]
//   eidx       int[1600000]       @ 294272
//   xb         bf16[100032*64]    @ 1894272  (3201024 ints, 16B aligned)
//   ebuf       u32[1600000]       @ 1894272  (aliases xb head; dead before k_gather)
// memset covers stats+ss+bucket_cnt = 2624 B @ int offset 100000

__device__ __forceinline__ unsigned short f2bf(float x) {
    unsigned int u = __float_as_uint(x);
    unsigned int r = (u + 0x7FFFu + ((u >> 16) & 1u)) >> 16;
    return (unsigned short)r;
}

// ---------------------------------------------------------------------------
// Pass A: per-chunk LDS counting sort by coarse bucket (dst>>8).
// Output: ebuf[e0..e0+n) = packed (src<<8 | dst&255) grouped by bucket within
// the chunk; runoff[blk][b] = local exclusive start of bucket b in this chunk;
// bucket_cnt[b] += per-chunk bucket count. All global writes fully coalesced.
// ---------------------------------------------------------------------------
__global__ __launch_bounds__(1024) void kA_scatter(const int* __restrict__ src,
                                                   const int* __restrict__ dst,
                                                   unsigned int* __restrict__ ebuf,
                                                   int* __restrict__ runoff,
                                                   int* __restrict__ bucket_cnt) {
    __shared__ int hist[NBUCK];
    __shared__ int ebase[NBUCK];
    __shared__ int sc[512];
    __shared__ unsigned int stage[SCHUNK];
    const int t = threadIdx.x;
    const int e0 = blockIdx.x * SCHUNK;
    const int n = min(SCHUNK, N_EDGES - e0);

    for (int i = t; i < NBUCK; i += 1024) hist[i] = 0;
    __syncthreads();
    for (int i = t; i < n; i += 1024)
        atomicAdd(&hist[dst[e0 + i] >> 8], 1);
    __syncthreads();

    // exclusive scan of hist over 391 entries (padded to 512)
    if (t < 512) sc[t] = (t < NBUCK) ? hist[t] : 0;
    __syncthreads();
    for (int off = 1; off < 512; off <<= 1) {
        int add = (t < 512 && t >= off) ? sc[t - off] : 0;
        __syncthreads();
        if (t < 512) sc[t] += add;
        __syncthreads();
    }
    if (t < NBUCK) {
        int ex = sc[t] - hist[t];
        ebase[t] = ex;
        runoff[blockIdx.x * RSTRIDE + t] = ex;
        if (hist[t] > 0) atomicAdd(&bucket_cnt[t], hist[t]);
    }
    if (t == 0) runoff[blockIdx.x * RSTRIDE + NBUCK] = n;
    if (t < NBUCK) hist[t] = 0;
    __syncthreads();

    // local scatter into LDS, sorted by bucket
    for (int i = t; i < n; i += 1024) {
        int d = dst[e0 + i];
        int s = src[e0 + i];
        int b = d >> 8;
        int r = atomicAdd(&hist[b], 1);
        stage[ebase[b] + r] = ((unsigned int)s << 8) | (unsigned int)(d & 255);
    }
    __syncthreads();
    // streaming coalesced write-back to this chunk's own region
    for (int i = t; i < n; i += 1024)
        ebuf[e0 + i] = stage[i];
}

// exclusive scan of bucket_cnt -> bucket_off[0..NBUCK]
__global__ __launch_bounds__(512) void kA_scan(const int* __restrict__ bucket_cnt,
                                               int* __restrict__ bucket_off) {
    __shared__ int sc[512];
    const int t = threadIdx.x;
    int v = (t < NBUCK) ? bucket_cnt[t] : 0;
    sc[t] = v;
    __syncthreads();
    for (int off = 1; off < 512; off <<= 1) {
        int add = (t >= off) ? sc[t - off] : 0;
        __syncthreads();
        sc[t] += add;
        __syncthreads();
    }
    if (t <= NBUCK) bucket_off[t] = sc[t] - v;   // t==NBUCK: v=0 -> total
}

// ---------------------------------------------------------------------------
// Pass B: one block per bucket. Gather the bucket's edges from its 196 runs,
// build per-node deg/offsets via LDS histogram+scan, sort src by node in LDS,
// write final CSR eidx with coalesced stores.
// ---------------------------------------------------------------------------
__global__ __launch_bounds__(1024) void kB_build(const unsigned int* __restrict__ ebuf,
                                                 const int* __restrict__ runoff,
                                                 const int* __restrict__ bucket_off,
                                                 int* __restrict__ deg,
                                                 int* __restrict__ offsets,
                                                 int* __restrict__ eidx) {
    __shared__ int runbase[SBLK + 1];
    __shared__ int runstart[SBLK];
    __shared__ int sc[256];
    __shared__ int cnt[256];
    __shared__ int off[256];
    __shared__ unsigned int stage2[MAXB];
    __shared__ unsigned int sout[MAXB];
    const int t = threadIdx.x;
    const int b = blockIdx.x;

    int rl = 0;
    if (t < SBLK) {
        int s = runoff[t * RSTRIDE + b];
        int e = runoff[t * RSTRIDE + b + 1];
        runstart[t] = t * SCHUNK + s;
        rl = e - s;
    }
    if (t < 256) { sc[t] = (t < SBLK) ? rl : 0; cnt[t] = 0; }
    __syncthreads();
    for (int o = 1; o < 256; o <<= 1) {
        int add = (t < 256 && t >= o) ? sc[t - o] : 0;
        __syncthreads();
        if (t < 256) sc[t] += add;
        __syncthreads();
    }
    if (t < SBLK) runbase[t] = sc[t] - rl;
    if (t == 0) runbase[SBLK] = sc[255];
    __syncthreads();
    const int total = runbase[SBLK];

    // gather this bucket's edges (segmented copy over 196 runs) + node histogram
    for (int idx = t; idx < total; idx += 1024) {
        int lo = 0, hi = SBLK - 1;                 // largest r: runbase[r] <= idx
        while (lo < hi) {
            int mid = (lo + hi + 1) >> 1;
            if (runbase[mid] <= idx) lo = mid; else hi = mid - 1;
        }
        unsigned int v = ebuf[runstart[lo] + (idx - runbase[lo])];
        stage2[idx] = v;
        atomicAdd(&cnt[v & 255u], 1);
    }
    __syncthreads();

    // deg + global offsets for this bucket's 256 nodes
    const int gn0 = b * 256;
    const int nn = min(256, N_NODES - gn0);
    int c = (t < 256) ? cnt[t] : 0;
    if (t < 256) sc[t] = c;
    __syncthreads();
    for (int o = 1; o < 256; o <<= 1) {
        int add = (t < 256 && t >= o) ? sc[t - o] : 0;
        __syncthreads();
        if (t < 256) sc[t] += add;
        __syncthreads();
    }
    if (t < 256) { off[t] = sc[t] - c; cnt[t] = 0; }
    if (t < nn) {
        deg[gn0 + t] = c;
        offsets[gn0 + t] = bucket_off[b] + off[t];
    }
    __syncthreads();

    // sort src by node into LDS
    for (int idx = t; idx < total; idx += 1024) {
        unsigned int v = stage2[idx];
        int node = (int)(v & 255u);
        int r = atomicAdd(&cnt[node], 1);
        sout[off[node] + r] = v >> 8;
    }
    __syncthreads();
    const int base = bucket_off[b];
    for (int idx = t; idx < total; idx += 1024)
        eidx[base + idx] = (int)sout[idx];
}

// weight prep: w1t_g[n][k]=bf16(W1[k][n]); w2t_g[d][k2]=bf16(W2[k2][d]); zero x pad
__global__ __launch_bounds__(256) void k_wprep(const float* __restrict__ W1,
                                               const float* __restrict__ W2,
                                               unsigned short* __restrict__ w1t,
                                               unsigned short* __restrict__ w2t,
                                               unsigned short* __restrict__ xb) {
    int id = blockIdx.x * 256 + threadIdx.x;     // 136*256 = 34816
    if (id < 16384) {                            // n*64+k
        int n = id >> 6, k = id & 63;
        w1t[id] = f2bf(W1[k * 256 + n]);
    } else if (id < 32768) {
        int i2 = id - 16384;                     // d*256+k2
        int d = i2 >> 8, k2 = i2 & 255;
        w2t[i2] = f2bf(W2[k2 * 64 + d]);
    } else {                                     // zero 32 pad rows of xb
        xb[100000 * 64 + (id - 32768)] = 0;
    }
}

// one wave per node: mean-gather + self, write bf16 x
__global__ __launch_bounds__(256) void k_gather(const float* __restrict__ h,
                                                const int* __restrict__ offsets,
                                                const int* __restrict__ deg,
                                                const int* __restrict__ eidx,
                                                unsigned short* __restrict__ xb) {
    const int lane = threadIdx.x & 63;
    const int node = blockIdx.x * 4 + (threadIdx.x >> 6);   // 25000*4 = 100000
    const int off = __builtin_amdgcn_readfirstlane(offsets[node]);
    const int dg  = __builtin_amdgcn_readfirstlane(deg[node]);
    const float* hl = h + lane;
    float own = hl[(size_t)node * 64];
    float s0 = 0.f, s1 = 0.f, s2 = 0.f, s3 = 0.f;
    int j = off, end = off + dg;
    for (; j + 3 < end; j += 4) {
        int a = eidx[j], b = eidx[j + 1], c = eidx[j + 2], d = eidx[j + 3];
        s0 += hl[(size_t)a * 64];
        s1 += hl[(size_t)b * 64];
        s2 += hl[(size_t)c * 64];
        s3 += hl[(size_t)d * 64];
    }
    for (; j < end; ++j) s0 += hl[(size_t)eidx[j] * 64];
    float x = (s0 + s1) + (s2 + s3);
    x = x / (float)max(dg, 1) + own;
    xb[(size_t)node * 64 + lane] = f2bf(x);
}

// fused 2-layer MFMA MLP + stats accumulation
__global__ __launch_bounds__(256, 2) void k_mlp(const unsigned short* __restrict__ xb,
                                                const unsigned short* __restrict__ w1t,
                                                const unsigned short* __restrict__ w2t,
                                                const float* __restrict__ b1,
                                                const float* __restrict__ b2,
                                                float* __restrict__ y,
                                                float* __restrict__ stats) {
    __shared__ unsigned short sW1[256][72];   // [n][k]  36864 B (2-way banks: free)
    __shared__ unsigned short sW2[64][264];   // [d][k2] 33792 B
    __shared__ unsigned short sH[4][16][72];  // per-wave hidden chunk [m][k2l] 9216 B
    __shared__ float sB1[256];
    __shared__ float sB2[64];
    const int t = threadIdx.x;
    const int lane = t & 63;
    const int w = t >> 6;
    const int l15 = lane & 15;
    const int g4 = lane >> 4;       // 0..3

    // stage weights (bf16, pre-transposed) into LDS, 16B chunks
    for (int i = t; i < 2048; i += 256) {          // W1t: 256 rows x 8 chunks
        int row = i >> 3, c = i & 7;
        *(uint4*)&sW1[row][c * 8] = *(const uint4*)(w1t + row * 64 + c * 8);
    }
    for (int i = t; i < 2048; i += 256) {          // W2t: 64 rows x 32 chunks
        int row = i >> 5, c = i & 31;
        *(uint4*)&sW2[row][c * 8] = *(const uint4*)(w2t + row * 256 + c * 8);
    }
    sB1[t] = b1[t];
    if (t < 64) sB2[t] = b2[t];
    __syncthreads();

    float lsum[4] = {0.f, 0.f, 0.f, 0.f};
    float lsq[4]  = {0.f, 0.f, 0.f, 0.f};

    for (int g = blockIdx.x; g < NGROUPS; g += MLP_BLOCKS) {
        const int m0 = g * 64 + w * 16;
        // x B-fragments (x^T as B operand): lane holds x[m0+l15][s*32+g4*8 .. +7]
        const unsigned short* xrow = xb + (size_t)(m0 + l15) * 64 + g4 * 8;
        bf16x8 xf0 = *(const bf16x8*)(xrow);
        bf16x8 xf1 = *(const bf16x8*)(xrow + 32);

        f32x4 oacc[4];
#pragma unroll
        for (int dt = 0; dt < 4; ++dt) oacc[dt] = (f32x4){0.f, 0.f, 0.f, 0.f};

#pragma unroll
        for (int p = 0; p < 4; ++p) {             // k2 chunks of 64
#pragma unroll
            for (int nt2 = 0; nt2 < 4; ++nt2) {   // L1: hidden^T tiles
                const int n0 = p * 64 + nt2 * 16;
                f32x4 hacc = (f32x4){0.f, 0.f, 0.f, 0.f};
                bf16x8 wf0 = *(const bf16x8*)&sW1[n0 + l15][g4 * 8];
                bf16x8 wf1 = *(const bf16x8*)&sW1[n0 + l15][32 + g4 * 8];
                hacc = __builtin_amdgcn_mfma_f32_16x16x32_bf16(wf0, xf0, hacc, 0, 0, 0);
                hacc = __builtin_amdgcn_mfma_f32_16x16x32_bf16(wf1, xf1, hacc, 0, 0, 0);
                // lane holds hidden[m=l15][n = n0 + g4*4 + r]
                float4 bq = *(const float4*)&sB1[n0 + g4 * 4];
                ushort4 pk;
                pk.x = f2bf(fmaxf(hacc[0] + bq.x, 0.f));
                pk.y = f2bf(fmaxf(hacc[1] + bq.y, 0.f));
                pk.z = f2bf(fmaxf(hacc[2] + bq.z, 0.f));
                pk.w = f2bf(fmaxf(hacc[3] + bq.w, 0.f));
                *(ushort4*)&sH[w][l15][nt2 * 16 + g4 * 4] = pk;
            }
#pragma unroll
            for (int s2 = 0; s2 < 2; ++s2) {      // L2 partial over this chunk
                bf16x8 a2 = *(const bf16x8*)&sH[w][l15][s2 * 32 + g4 * 8];
#pragma unroll
                for (int dt = 0; dt < 4; ++dt) {
                    bf16x8 w2f = *(const bf16x8*)&sW2[dt * 16 + l15]
                                                    [p * 64 + s2 * 32 + g4 * 8];
                    oacc[dt] = __builtin_amdgcn_mfma_f32_16x16x32_bf16(
                        a2, w2f, oacc[dt], 0, 0, 0);
                }
            }
        }
        // epilogue: bias + relu, store y, accumulate stats
#pragma unroll
        for (int dt = 0; dt < 4; ++dt) {
            float bv = sB2[dt * 16 + l15];
#pragma unroll
            for (int r = 0; r < 4; ++r) {
                int mabs = m0 + g4 * 4 + r;
                float val = fmaxf(oacc[dt][r] + bv, 0.f);
                if (mabs < N_NODES) {
                    y[(size_t)mabs * 64 + dt * 16 + l15] = val;
                    lsum[dt] += val;
                    lsq[dt] += val * val;
                }
            }
        }
    }

    // block-level stats reduction (reuse sW1 memory)
    __syncthreads();
    float* sred = (float*)&sW1[0][0];             // [256][8]
#pragma unroll
    for (int dt = 0; dt < 4; ++dt) {
        sred[t * 8 + dt] = lsum[dt];
        sred[t * 8 + 4 + dt] = lsq[dt];
    }
    __syncthreads();
    if (t < 128) {
        int issq = (t >= 64) ? 4 : 0;
        int d = t & 63;
        int dt = d >> 4, dl = d & 15;
        float acc = 0.f;
        for (int i = 0; i < 16; ++i) acc += sred[(dl + 16 * i) * 8 + issq + dt];
        atomicAdd(&stats[(issq ? 64 : 0) + d], acc);
    }
}

__global__ void k_bnfin(const float* __restrict__ stats,
                        const float* __restrict__ gamma,
                        const float* __restrict__ beta,
                        float* __restrict__ ss) {
    int d = threadIdx.x;
    if (d < 64) {
        const float inv_n = 1.0f / (float)N_NODES;
        float m = stats[d] * inv_n;
        float v = stats[64 + d] * inv_n - m * m;
        float sc = gamma[d] * rsqrtf(v + BN_EPS);
        ss[d] = sc;
        ss[64 + d] = beta[d] - m * sc;
    }
}

__global__ __launch_bounds__(256) void k_apply(const float* __restrict__ ss,
                                               float* __restrict__ out) {
    int i = blockIdx.x * 256 + threadIdx.x;
    if (i >= N_NODES * 16) return;
    float4 v = ((float4*)out)[i];
    int q = i & 15;
    float4 sc = ((const float4*)ss)[q];
    float4 sh = ((const float4*)ss)[16 + q];
    float4 o;
    o.x = fmaf(v.x, sc.x, sh.x);
    o.y = fmaf(v.y, sc.y, sh.y);
    o.z = fmaf(v.z, sc.z, sh.z);
    o.w = fmaf(v.w, sc.w, sh.w);
    ((float4*)out)[i] = o;
}

extern "C" void kernel_launch(void* const* d_in, const int* in_sizes, int n_in,
                              void* d_out, int out_size, void* d_ws, size_t ws_size,
                              hipStream_t stream) {
    const float* h     = (const float*)d_in[0];
    const float* W1    = (const float*)d_in[1];
    const float* b1    = (const float*)d_in[2];
    const float* W2    = (const float*)d_in[3];
    const float* b2    = (const float*)d_in[4];
    const float* gamma = (const float*)d_in[5];
    const float* beta  = (const float*)d_in[6];
    const int*   src   = (const int*)d_in[7];
    const int*   dst   = (const int*)d_in[8];

    int* wsi = (int*)d_ws;
    int*            deg        = wsi;                              // 100000
    float*          stats      = (float*)(wsi + 100000);           // 128
    float*          ss         = (float*)(wsi + 100128);           // 128
    int*            bucket_cnt = wsi + 100256;                     // 400
    int*            bucket_off = wsi + 100656;                     // 400
    int*            offsets    = wsi + 101056;                     // 100000
    int*            runoff     = wsi + 201056;                     // 76832
    unsigned short* w1t        = (unsigned short*)(wsi + 277888);  // 8192 ints
    unsigned short* w2t        = (unsigned short*)(wsi + 286080);  // 8192 ints
    int*            eidx       = wsi + 294272;                     // 1600000
    unsigned short* xb         = (unsigned short*)(wsi + 1894272); // 3201024 ints
    unsigned int*   ebuf       = (unsigned int*)(wsi + 1894272);   // aliases xb head
    float*          out        = (float*)d_out;

    // zero stats + ss + bucket_cnt (contiguous: 2624 B)
    hipMemsetAsync(wsi + 100000, 0, 2624, stream);

    kA_scatter<<<SBLK, 1024, 0, stream>>>(src, dst, ebuf, runoff, bucket_cnt);
    kA_scan<<<1, 512, 0, stream>>>(bucket_cnt, bucket_off);
    kB_build<<<NBUCK, 1024, 0, stream>>>(ebuf, runoff, bucket_off, deg, offsets, eidx);
    k_wprep<<<136, 256, 0, stream>>>(W1, W2, w1t, w2t, xb);
    k_gather<<<25000, 256, 0, stream>>>(h, offsets, deg, eidx, xb);
    k_mlp<<<MLP_BLOCKS, 256, 0, stream>>>(xb, w1t, w2t, b1, b2, out, stats);
    k_bnfin<<<1, 64, 0, stream>>>(stats, gamma, beta, ss);
    k_apply<<<(N_NODES * 16 + 255) / 256, 256, 0, stream>>>(ss, out);
}

// Round 2
// 217.561 us; speedup vs baseline: 1.9041x; 1.1461x over previous
//
#include <hip/hip_runtime.h>

#define N_NODES 100000
#define N_EDGES 1600000
#define DIM     64
#define HID     256
#define BN_EPS  1e-5f

// counting-sort parameters
#define NBUCK   391            // ceil(100000/256) buckets of 256 nodes
#define RSTRIDE 392            // runoff row stride (NBUCK + 1 for chunk total)
#define SCHUNK  8192           // edges per kA_scatter block
#define SBLK    196            // ceil(1600000/8192)
#define MAXB    6144           // max edges per bucket

// MLP parameters
#define XBROWS  100032         // padded xb rows
#define NGP     782            // ceil(100032/128) block-iterations of 128 rows
#define MLPGRID 256            // 1 block/CU

typedef short bf16x8 __attribute__((ext_vector_type(8)));
typedef float f32x4  __attribute__((ext_vector_type(4)));

// ws layout (4-byte units):
//   deg        int[100000]        @ 0
//   stats      float[128]         @ 100000   (sum[64], sumsq[64])     [zeroed]
//   ss         float[128]         @ 100128   (scale[64], shift[64])
//   bucket_cnt int[400]           @ 100256                            [zeroed]
//   bucket_off int[400]           @ 100656
//   offsets    int[100000]        @ 101056
//   runoff     int[196*392]       @ 201056   (76832; reused as dump scratch by k_out)
//   w1t_g      bf16[256*64]       @ 277888   (8192 ints)  [n][k] chunk-swizzled
//   w2t_g      bf16[64*256]       @ 286080   (8192 ints)  [d][k2] chunk-swizzled
//   eidx       int[1600000]       @ 294272
//   xb         bf16[100032*64]    @ 1894272  (3201024 ints) chunk-swizzled rows
//   ebuf       u32[1600000]       @ 1894272  (aliases xb head; dead before k_gather)

__device__ __forceinline__ unsigned short f2bf(float x) {
    unsigned int u = __float_as_uint(x);
    unsigned int r = (u + 0x7FFFu + ((u >> 16) & 1u)) >> 16;
    return (unsigned short)r;
}

#define WAITV(N) asm volatile("s_waitcnt vmcnt(" #N ")" ::: "memory")

// issue 2x global_load_lds(16B) staging 16 rows (2048 B) into per-wave LDS buffer.
// gsrc is per-lane: xb + row0*64 + lane*8 ; LDS dest is wave-uniform base.
__device__ __forceinline__ void stage_issue(const unsigned short* gsrc,
                                            unsigned short* ldst) {
    __builtin_amdgcn_global_load_lds(
        (const __attribute__((address_space(1))) void*)gsrc,
        (__attribute__((address_space(3))) void*)ldst, 16, 0, 0);
    __builtin_amdgcn_global_load_lds(
        (const __attribute__((address_space(1))) void*)(gsrc + 512),
        (__attribute__((address_space(3))) void*)(ldst + 512), 16, 0, 0);
}

// ---------------------------------------------------------------------------
// Pass A: per-chunk LDS counting sort by coarse bucket (dst>>8).
// ---------------------------------------------------------------------------
__global__ __launch_bounds__(1024) void kA_scatter(const int* __restrict__ src,
                                                   const int* __restrict__ dst,
                                                   unsigned int* __restrict__ ebuf,
                                                   int* __restrict__ runoff,
                                                   int* __restrict__ bucket_cnt) {
    __shared__ int hist[NBUCK];
    __shared__ int ebase[NBUCK];
    __shared__ int sc[512];
    __shared__ unsigned int stage[SCHUNK];
    const int t = threadIdx.x;
    const int e0 = blockIdx.x * SCHUNK;
    const int n = min(SCHUNK, N_EDGES - e0);

    for (int i = t; i < NBUCK; i += 1024) hist[i] = 0;
    __syncthreads();
    for (int i = t; i < n; i += 1024)
        atomicAdd(&hist[dst[e0 + i] >> 8], 1);
    __syncthreads();

    if (t < 512) sc[t] = (t < NBUCK) ? hist[t] : 0;
    __syncthreads();
    for (int off = 1; off < 512; off <<= 1) {
        int add = (t < 512 && t >= off) ? sc[t - off] : 0;
        __syncthreads();
        if (t < 512) sc[t] += add;
        __syncthreads();
    }
    if (t < NBUCK) {
        int ex = sc[t] - hist[t];
        ebase[t] = ex;
        runoff[blockIdx.x * RSTRIDE + t] = ex;
        if (hist[t] > 0) atomicAdd(&bucket_cnt[t], hist[t]);
    }
    if (t == 0) runoff[blockIdx.x * RSTRIDE + NBUCK] = n;
    if (t < NBUCK) hist[t] = 0;
    __syncthreads();

    for (int i = t; i < n; i += 1024) {
        int d = dst[e0 + i];
        int s = src[e0 + i];
        int b = d >> 8;
        int r = atomicAdd(&hist[b], 1);
        stage[ebase[b] + r] = ((unsigned int)s << 8) | (unsigned int)(d & 255);
    }
    __syncthreads();
    for (int i = t; i < n; i += 1024)
        ebuf[e0 + i] = stage[i];
}

__global__ __launch_bounds__(512) void kA_scan(const int* __restrict__ bucket_cnt,
                                               int* __restrict__ bucket_off) {
    __shared__ int sc[512];
    const int t = threadIdx.x;
    int v = (t < NBUCK) ? bucket_cnt[t] : 0;
    sc[t] = v;
    __syncthreads();
    for (int off = 1; off < 512; off <<= 1) {
        int add = (t >= off) ? sc[t - off] : 0;
        __syncthreads();
        sc[t] += add;
        __syncthreads();
    }
    if (t <= NBUCK) bucket_off[t] = sc[t] - v;
}

// ---------------------------------------------------------------------------
// Pass B: one block per bucket -> deg/offsets + final CSR eidx.
// ---------------------------------------------------------------------------
__global__ __launch_bounds__(1024) void kB_build(const unsigned int* __restrict__ ebuf,
                                                 const int* __restrict__ runoff,
                                                 const int* __restrict__ bucket_off,
                                                 int* __restrict__ deg,
                                                 int* __restrict__ offsets,
                                                 int* __restrict__ eidx) {
    __shared__ int runbase[SBLK + 1];
    __shared__ int runstart[SBLK];
    __shared__ int sc[256];
    __shared__ int cnt[256];
    __shared__ int off[256];
    __shared__ unsigned int stage2[MAXB];
    __shared__ unsigned int sout[MAXB];
    const int t = threadIdx.x;
    const int b = blockIdx.x;

    int rl = 0;
    if (t < SBLK) {
        int s = runoff[t * RSTRIDE + b];
        int e = runoff[t * RSTRIDE + b + 1];
        runstart[t] = t * SCHUNK + s;
        rl = e - s;
    }
    if (t < 256) { sc[t] = (t < SBLK) ? rl : 0; cnt[t] = 0; }
    __syncthreads();
    for (int o = 1; o < 256; o <<= 1) {
        int add = (t < 256 && t >= o) ? sc[t - o] : 0;
        __syncthreads();
        if (t < 256) sc[t] += add;
        __syncthreads();
    }
    if (t < SBLK) runbase[t] = sc[t] - rl;
    if (t == 0) runbase[SBLK] = sc[255];
    __syncthreads();
    const int total = runbase[SBLK];

    for (int idx = t; idx < total; idx += 1024) {
        int lo = 0, hi = SBLK - 1;
        while (lo < hi) {
            int mid = (lo + hi + 1) >> 1;
            if (runbase[mid] <= idx) lo = mid; else hi = mid - 1;
        }
        unsigned int v = ebuf[runstart[lo] + (idx - runbase[lo])];
        stage2[idx] = v;
        atomicAdd(&cnt[v & 255u], 1);
    }
    __syncthreads();

    const int gn0 = b * 256;
    const int nn = min(256, N_NODES - gn0);
    int c = (t < 256) ? cnt[t] : 0;
    if (t < 256) sc[t] = c;
    __syncthreads();
    for (int o = 1; o < 256; o <<= 1) {
        int add = (t < 256 && t >= o) ? sc[t - o] : 0;
        __syncthreads();
        if (t < 256) sc[t] += add;
        __syncthreads();
    }
    if (t < 256) { off[t] = sc[t] - c; cnt[t] = 0; }
    if (t < nn) {
        deg[gn0 + t] = c;
        offsets[gn0 + t] = bucket_off[b] + off[t];
    }
    __syncthreads();

    for (int idx = t; idx < total; idx += 1024) {
        unsigned int v = stage2[idx];
        int node = (int)(v & 255u);
        int r = atomicAdd(&cnt[node], 1);
        sout[off[node] + r] = v >> 8;
    }
    __syncthreads();
    const int base = bucket_off[b];
    for (int idx = t; idx < total; idx += 1024)
        eidx[base + idx] = (int)sout[idx];
}

// weight prep (chunk-swizzled): phys chunk = (logical chunk) ^ (row&7)
__global__ __launch_bounds__(256) void k_wprep(const float* __restrict__ W1,
                                               const float* __restrict__ W2,
                                               unsigned short* __restrict__ w1t,
                                               unsigned short* __restrict__ w2t,
                                               unsigned short* __restrict__ xb) {
    int id = blockIdx.x * 256 + threadIdx.x;     // 136*256 = 34816
    if (id < 16384) {                            // n*64+k
        int n = id >> 6, k = id & 63;
        int dstp = (n << 6) + ((((k >> 3) ^ (n & 7))) << 3) + (k & 7);
        w1t[dstp] = f2bf(W1[k * 256 + n]);
    } else if (id < 32768) {
        int i2 = id - 16384;                     // d*256+k2
        int d = i2 >> 8, k2 = i2 & 255;
        int dstp = (d << 8) + ((((k2 >> 3) ^ (d & 7))) << 3) + (k2 & 7);
        w2t[dstp] = f2bf(W2[k2 * 64 + d]);
    } else {                                     // zero 32 pad rows of xb
        xb[100000 * 64 + (id - 32768)] = 0;
    }
}

// one wave per node: mean-gather + self, write bf16 x (chunk-swizzled row)
__global__ __launch_bounds__(256) void k_gather(const float* __restrict__ h,
                                                const int* __restrict__ offsets,
                                                const int* __restrict__ deg,
                                                const int* __restrict__ eidx,
                                                unsigned short* __restrict__ xb) {
    const int lane = threadIdx.x & 63;
    const int node = blockIdx.x * 4 + (threadIdx.x >> 6);
    const int off = __builtin_amdgcn_readfirstlane(offsets[node]);
    const int dg  = __builtin_amdgcn_readfirstlane(deg[node]);
    const float* hl = h + lane;
    float own = hl[(size_t)node * 64];
    float s0 = 0.f, s1 = 0.f, s2 = 0.f, s3 = 0.f;
    int j = off, end = off + dg;
    for (; j + 3 < end; j += 4) {
        int a = eidx[j], b = eidx[j + 1], c = eidx[j + 2], d = eidx[j + 3];
        s0 += hl[(size_t)a * 64];
        s1 += hl[(size_t)b * 64];
        s2 += hl[(size_t)c * 64];
        s3 += hl[(size_t)d * 64];
    }
    for (; j < end; ++j) s0 += hl[(size_t)eidx[j] * 64];
    float x = (s0 + s1) + (s2 + s3);
    x = x / (float)max(dg, 1) + own;
    int dstE = node * 64 + (((lane >> 3) ^ (node & 7)) << 3) + (lane & 7);
    xb[dstE] = f2bf(x);
}

// ---------------------------------------------------------------------------
// Fused MLP core: per-wave 16-row tile from swizzled LDS; weights in swizzled
// LDS; hidden relayout via per-wave swizzled sH. All frag ds_reads balanced.
// ---------------------------------------------------------------------------
__device__ __forceinline__ void mlp_tile(const unsigned short* sXw,
                                         const unsigned short* sW1,
                                         const unsigned short* sW2,
                                         unsigned short* sHw,
                                         const float* sB1,
                                         int l15, int g4, int s7,
                                         f32x4 oacc[4]) {
    bf16x8 xf0 = *(const bf16x8*)&sXw[l15 * 64 + ((g4 ^ s7) << 3)];
    bf16x8 xf1 = *(const bf16x8*)&sXw[l15 * 64 + (((g4 + 4) ^ s7) << 3)];
#pragma unroll
    for (int dt = 0; dt < 4; ++dt) oacc[dt] = (f32x4){0.f, 0.f, 0.f, 0.f};

#pragma unroll
    for (int p = 0; p < 4; ++p) {
#pragma unroll
        for (int nt2 = 0; nt2 < 4; ++nt2) {
            const int n0 = p * 64 + nt2 * 16;
            f32x4 hacc = (f32x4){0.f, 0.f, 0.f, 0.f};
            bf16x8 wf0 = *(const bf16x8*)&sW1[(n0 + l15) * 64 + ((g4 ^ s7) << 3)];
            bf16x8 wf1 = *(const bf16x8*)&sW1[(n0 + l15) * 64 + (((g4 + 4) ^ s7) << 3)];
            hacc = __builtin_amdgcn_mfma_f32_16x16x32_bf16(wf0, xf0, hacc, 0, 0, 0);
            hacc = __builtin_amdgcn_mfma_f32_16x16x32_bf16(wf1, xf1, hacc, 0, 0, 0);
            float4 bq = *(const float4*)&sB1[n0 + g4 * 4];
            ushort4 pk;
            pk.x = f2bf(fmaxf(hacc[0] + bq.x, 0.f));
            pk.y = f2bf(fmaxf(hacc[1] + bq.y, 0.f));
            pk.z = f2bf(fmaxf(hacc[2] + bq.z, 0.f));
            pk.w = f2bf(fmaxf(hacc[3] + bq.w, 0.f));
            int qh = nt2 * 2 + (g4 >> 1);
            *(ushort4*)&sHw[l15 * 64 + ((qh ^ s7) << 3) + ((g4 & 1) << 2)] = pk;
        }
#pragma unroll
        for (int s2 = 0; s2 < 2; ++s2) {
            bf16x8 a2 = *(const bf16x8*)&sHw[l15 * 64 + (((s2 * 4 + g4) ^ s7) << 3)];
#pragma unroll
            for (int dt = 0; dt < 4; ++dt) {
                int q = p * 8 + s2 * 4 + g4;
                bf16x8 w2f = *(const bf16x8*)&sW2[(dt * 16 + l15) * 256 + ((q ^ s7) << 3)];
                oacc[dt] = __builtin_amdgcn_mfma_f32_16x16x32_bf16(a2, w2f, oacc[dt], 0, 0, 0);
            }
        }
    }
}

// pass 1: MLP -> BN stats only (no stores)
__global__ __launch_bounds__(512, 2) void k_stats(const unsigned short* __restrict__ xb,
                                                  const unsigned short* __restrict__ w1t,
                                                  const unsigned short* __restrict__ w2t,
                                                  const float* __restrict__ b1,
                                                  const float* __restrict__ b2,
                                                  float* __restrict__ stats) {
    __shared__ unsigned short sW1[256 * 64];
    __shared__ unsigned short sW2[64 * 256];
    __shared__ unsigned short sH[8][16 * 64];
    __shared__ unsigned short sX[8][2][16 * 64];
    __shared__ float sB1[256];
    const int t = threadIdx.x;
    const int lane = t & 63;
    const int w = t >> 6;
    const int l15 = lane & 15;
    const int g4 = lane >> 4;
    const int s7 = l15 & 7;

    for (int i = t; i < 2048; i += 512)
        *(uint4*)&sW1[i * 8] = *(const uint4*)&w1t[i * 8];
    for (int i = t; i < 2048; i += 512)
        *(uint4*)&sW2[i * 8] = *(const uint4*)&w2t[i * 8];
    if (t < 256) sB1[t] = b1[t];
    __syncthreads();

    float b2v[4];
#pragma unroll
    for (int dt = 0; dt < 4; ++dt) b2v[dt] = b2[dt * 16 + l15];

    float lsum[4] = {0.f, 0.f, 0.f, 0.f};
    float lsq[4]  = {0.f, 0.f, 0.f, 0.f};

    int cur = 0;
    {
        int r0 = min((int)blockIdx.x * 128 + w * 16, XBROWS - 16);
        stage_issue(xb + (size_t)r0 * 64 + lane * 8, &sX[w][0][0]);
    }
    for (int gp = blockIdx.x; gp < NGP; gp += MLPGRID) {
        int gpn = (gp + MLPGRID < NGP) ? gp + MLPGRID : gp;
        int r0n = min(gpn * 128 + w * 16, XBROWS - 16);
        stage_issue(xb + (size_t)r0n * 64 + lane * 8, &sX[w][cur ^ 1][0]);
        WAITV(2);
        __builtin_amdgcn_sched_barrier(0);
        const int row0 = gp * 128 + w * 16;
        if (row0 < XBROWS) {
            f32x4 oacc[4];
            mlp_tile(&sX[w][cur][0], sW1, sW2, &sH[w][0], sB1, l15, g4, s7, oacc);
#pragma unroll
            for (int dt = 0; dt < 4; ++dt) {
#pragma unroll
                for (int r = 0; r < 4; ++r) {
                    int mabs = row0 + g4 * 4 + r;
                    if (mabs < N_NODES) {
                        float val = fmaxf(oacc[dt][r] + b2v[dt], 0.f);
                        lsum[dt] += val;
                        lsq[dt] += val * val;
                    }
                }
            }
        }
        cur ^= 1;
    }

    __syncthreads();
    float* sred = (float*)&sW1[0];                // [512][8] = 16 KB
#pragma unroll
    for (int dt = 0; dt < 4; ++dt) {
        sred[t * 8 + dt] = lsum[dt];
        sred[t * 8 + 4 + dt] = lsq[dt];
    }
    __syncthreads();
    if (t < 128) {
        int issq = (t >= 64) ? 4 : 0;
        int d = t & 63;
        int dt = d >> 4, dl = d & 15;
        float acc = 0.f;
        for (int i = 0; i < 32; ++i) acc += sred[(dl + 16 * i) * 8 + issq + dt];
        atomicAdd(&stats[(issq ? 64 : 0) + d], acc);
    }
}

__global__ void k_bnfin(const float* __restrict__ stats,
                        const float* __restrict__ gamma,
                        const float* __restrict__ beta,
                        float* __restrict__ ss) {
    int d = threadIdx.x;
    if (d < 64) {
        const float inv_n = 1.0f / (float)N_NODES;
        float m = stats[d] * inv_n;
        float v = stats[64 + d] * inv_n - m * m;
        float sc = gamma[d] * rsqrtf(v + BN_EPS);
        ss[d] = sc;
        ss[64 + d] = beta[d] - m * sc;
    }
}

// pass 2: recompute MLP, apply BN, write final out with full-line stores
__global__ __launch_bounds__(512, 2) void k_out(const unsigned short* __restrict__ xb,
                                                const unsigned short* __restrict__ w1t,
                                                const unsigned short* __restrict__ w2t,
                                                const float* __restrict__ b1,
                                                const float* __restrict__ b2,
                                                const float* __restrict__ ss,
                                                float* __restrict__ out,
                                                float* __restrict__ dump) {
    __shared__ unsigned short sW1[256 * 64];
    __shared__ unsigned short sW2[64 * 256];
    __shared__ unsigned short sH[8][16 * 64];
    __shared__ unsigned short sX[8][2][16 * 64];
    __shared__ float sB1[256];
    const int t = threadIdx.x;
    const int lane = t & 63;
    const int w = t >> 6;
    const int l15 = lane & 15;
    const int g4 = lane >> 4;
    const int s7 = l15 & 7;

    for (int i = t; i < 2048; i += 512)
        *(uint4*)&sW1[i * 8] = *(const uint4*)&w1t[i * 8];
    for (int i = t; i < 2048; i += 512)
        *(uint4*)&sW2[i * 8] = *(const uint4*)&w2t[i * 8];
    if (t < 256) sB1[t] = b1[t];
    __syncthreads();

    float b2v[4], scv[4], shv[4];
#pragma unroll
    for (int dt = 0; dt < 4; ++dt) {
        b2v[dt] = b2[dt * 16 + l15];
        scv[dt] = ss[dt * 16 + l15];
        shv[dt] = ss[64 + dt * 16 + l15];
    }

    int cur = 0;
    {
        int r0 = min((int)blockIdx.x * 128 + w * 16, XBROWS - 16);
        stage_issue(xb + (size_t)r0 * 64 + lane * 8, &sX[w][0][0]);
    }
    for (int gp = blockIdx.x; gp < NGP; gp += MLPGRID) {
        int gpn = (gp + MLPGRID < NGP) ? gp + MLPGRID : gp;
        int r0n = min(gpn * 128 + w * 16, XBROWS - 16);
        stage_issue(xb + (size_t)r0n * 64 + lane * 8, &sX[w][cur ^ 1][0]);
        if (gp == (int)blockIdx.x) { WAITV(2); } else { WAITV(6); }
        __builtin_amdgcn_sched_barrier(0);
        const int row0 = gp * 128 + w * 16;
        if (row0 < XBROWS) {
            f32x4 oacc[4];
            mlp_tile(&sX[w][cur][0], sW1, sW2, &sH[w][0], sB1, l15, g4, s7, oacc);
            // epilogue: bias+relu+BN, bounce 8-row halves through sH (as f32),
            // stream out as full-line float4 stores.
            float* sHf = (float*)&sH[w][0];       // [8][64] f32 = 2048 B
#pragma unroll
            for (int hh = 0; hh < 2; ++hh) {
                asm volatile("" ::: "memory");
                if ((g4 >> 1) == hh) {
#pragma unroll
                    for (int dt = 0; dt < 4; ++dt) {
#pragma unroll
                        for (int r = 0; r < 4; ++r) {
                            float val = fmaxf(oacc[dt][r] + b2v[dt], 0.f);
                            val = fmaf(val, scv[dt], shv[dt]);
                            sHf[((g4 & 1) * 4 + r) * 64 + dt * 16 + l15] = val;
                        }
                    }
                }
                asm volatile("" ::: "memory");
#pragma unroll
                for (int j = 0; j < 2; ++j) {
                    int rl = j * 4 + (lane >> 4);
                    int rg = row0 + hh * 8 + rl;
                    float4 v = *(const float4*)&sHf[rl * 64 + (lane & 15) * 4];
                    float* dstp = (rg < N_NODES)
                        ? &out[(size_t)rg * 64 + (lane & 15) * 4]
                        : &dump[lane * 4];
                    *(float4*)dstp = v;
                }
            }
        }
        cur ^= 1;
    }
}

extern "C" void kernel_launch(void* const* d_in, const int* in_sizes, int n_in,
                              void* d_out, int out_size, void* d_ws, size_t ws_size,
                              hipStream_t stream) {
    const float* h     = (const float*)d_in[0];
    const float* W1    = (const float*)d_in[1];
    const float* b1    = (const float*)d_in[2];
    const float* W2    = (const float*)d_in[3];
    const float* b2    = (const float*)d_in[4];
    const float* gamma = (const float*)d_in[5];
    const float* beta  = (const float*)d_in[6];
    const int*   src   = (const int*)d_in[7];
    const int*   dst   = (const int*)d_in[8];

    int* wsi = (int*)d_ws;
    int*            deg        = wsi;                              // 100000
    float*          stats      = (float*)(wsi + 100000);           // 128
    float*          ss         = (float*)(wsi + 100128);           // 128
    int*            bucket_cnt = wsi + 100256;                     // 400
    int*            bucket_off = wsi + 100656;                     // 400
    int*            offsets    = wsi + 101056;                     // 100000
    int*            runoff     = wsi + 201056;                     // 76832
    float*          dump       = (float*)(wsi + 201056);           // reuse (dead)
    unsigned short* w1t        = (unsigned short*)(wsi + 277888);  // 8192 ints
    unsigned short* w2t        = (unsigned short*)(wsi + 286080);  // 8192 ints
    int*            eidx       = wsi + 294272;                     // 1600000
    unsigned short* xb         = (unsigned short*)(wsi + 1894272); // 3201024 ints
    unsigned int*   ebuf       = (unsigned int*)(wsi + 1894272);   // aliases xb head
    float*          out        = (float*)d_out;

    // zero stats + ss + bucket_cnt (contiguous: 2624 B)
    hipMemsetAsync(wsi + 100000, 0, 2624, stream);

    kA_scatter<<<SBLK, 1024, 0, stream>>>(src, dst, ebuf, runoff, bucket_cnt);
    kA_scan<<<1, 512, 0, stream>>>(bucket_cnt, bucket_off);
    kB_build<<<NBUCK, 1024, 0, stream>>>(ebuf, runoff, bucket_off, deg, offsets, eidx);
    k_wprep<<<136, 256, 0, stream>>>(W1, W2, w1t, w2t, xb);
    k_gather<<<25000, 256, 0, stream>>>(h, offsets, deg, eidx, xb);
    k_stats<<<MLPGRID, 512, 0, stream>>>(xb, w1t, w2t, b1, b2, stats);
    k_bnfin<<<1, 64, 0, stream>>>(stats, gamma, beta, ss);
    k_out<<<MLPGRID, 512, 0, stream>>>(xb, w1t, w2t, b1, b2, ss, out, dump);
}

// Round 3
// 191.428 us; speedup vs baseline: 2.1641x; 1.1365x over previous
//
#include <hip/hip_runtime.h>

#define N_NODES 100000
#define N_EDGES 1600000
#define DIM     64
#define HID     256
#define BN_EPS  1e-5f

// counting-sort parameters
#define NBUCK   391            // ceil(100000/256) buckets of 256 nodes
#define RSTRIDE 392            // runoff row stride (NBUCK + 1 for chunk total)
#define SCHUNK  8192           // edges per kA_scatter block
#define SBLK    196            // ceil(1600000/8192)
#define MAXB    6144           // max edges per bucket

// MLP parameters
#define XBROWS  100032         // padded xb rows
#define NGP     782            // ceil(100032/128) block-iterations of 128 rows
#define MLPGRID 256            // 1 block/CU (LDS-forced); grid == CU count
#define MAXIT   4              // ceil(NGP/MLPGRID)

typedef short bf16x8 __attribute__((ext_vector_type(8)));
typedef float f32x4  __attribute__((ext_vector_type(4)));

// ws layout (4-byte units):
//   deg        int[100000]        @ 0
//   stats      float[128]         @ 100000   (sum[64], sumsq[64])     [zeroed]
//   bar        int[128]           @ 100128   (grid barrier, slot 0)   [zeroed]
//   bucket_cnt int[400]           @ 100256                            [zeroed]
//   bucket_off int[400]           @ 100656
//   offsets    int[100000]        @ 101056
//   runoff     int[196*392]       @ 201056   (76832; reused as dump scratch)
//   w1t_g      bf16[256*64]       @ 277888   (8192 ints)  [n][k] chunk-swizzled
//   w2t_g      bf16[64*256]       @ 286080   (8192 ints)  [d][k2] chunk-swizzled
//   eidx       int[1600000]       @ 294272
//   xb         bf16[100032*64]    @ 1894272  (3201024 ints) chunk-swizzled rows
//   ebuf       u32[1600000]       @ 1894272  (aliases xb head; dead before k_gather)
//   hb         bf16[100000*64]    @ 5095296  (3200000 ints) h in bf16, row-major
// memset covers stats+bar+bucket_cnt = 2624 B @ int offset 100000

__device__ __forceinline__ unsigned short f2bf(float x) {
    unsigned int u = __float_as_uint(x);
    unsigned int r = (u + 0x7FFFu + ((u >> 16) & 1u)) >> 16;
    return (unsigned short)r;
}

#define WAITV(N) asm volatile("s_waitcnt vmcnt(" #N ")" ::: "memory")

// issue 2x global_load_lds(16B) staging 16 rows (2048 B) into per-wave LDS buffer.
__device__ __forceinline__ void stage_issue(const unsigned short* gsrc,
                                            unsigned short* ldst) {
    __builtin_amdgcn_global_load_lds(
        (const __attribute__((address_space(1))) void*)gsrc,
        (__attribute__((address_space(3))) void*)ldst, 16, 0, 0);
    __builtin_amdgcn_global_load_lds(
        (const __attribute__((address_space(1))) void*)(gsrc + 512),
        (__attribute__((address_space(3))) void*)(ldst + 512), 16, 0, 0);
}

// ---------------------------------------------------------------------------
// Pass A: per-chunk LDS counting sort by coarse bucket (dst>>8).
// ---------------------------------------------------------------------------
__global__ __launch_bounds__(1024) void kA_scatter(const int* __restrict__ src,
                                                   const int* __restrict__ dst,
                                                   unsigned int* __restrict__ ebuf,
                                                   int* __restrict__ runoff,
                                                   int* __restrict__ bucket_cnt) {
    __shared__ int hist[NBUCK];
    __shared__ int ebase[NBUCK];
    __shared__ int sc[512];
    __shared__ unsigned int stage[SCHUNK];
    const int t = threadIdx.x;
    const int e0 = blockIdx.x * SCHUNK;
    const int n = min(SCHUNK, N_EDGES - e0);

    for (int i = t; i < NBUCK; i += 1024) hist[i] = 0;
    __syncthreads();
    for (int i = t; i < n; i += 1024)
        atomicAdd(&hist[dst[e0 + i] >> 8], 1);
    __syncthreads();

    if (t < 512) sc[t] = (t < NBUCK) ? hist[t] : 0;
    __syncthreads();
    for (int off = 1; off < 512; off <<= 1) {
        int add = (t < 512 && t >= off) ? sc[t - off] : 0;
        __syncthreads();
        if (t < 512) sc[t] += add;
        __syncthreads();
    }
    if (t < NBUCK) {
        int ex = sc[t] - hist[t];
        ebase[t] = ex;
        runoff[blockIdx.x * RSTRIDE + t] = ex;
        if (hist[t] > 0) atomicAdd(&bucket_cnt[t], hist[t]);
    }
    if (t == 0) runoff[blockIdx.x * RSTRIDE + NBUCK] = n;
    if (t < NBUCK) hist[t] = 0;
    __syncthreads();

    for (int i = t; i < n; i += 1024) {
        int d = dst[e0 + i];
        int s = src[e0 + i];
        int b = d >> 8;
        int r = atomicAdd(&hist[b], 1);
        stage[ebase[b] + r] = ((unsigned int)s << 8) | (unsigned int)(d & 255);
    }
    __syncthreads();
    for (int i = t; i < n; i += 1024)
        ebuf[e0 + i] = stage[i];
}

__global__ __launch_bounds__(512) void kA_scan(const int* __restrict__ bucket_cnt,
                                               int* __restrict__ bucket_off) {
    __shared__ int sc[512];
    const int t = threadIdx.x;
    int v = (t < NBUCK) ? bucket_cnt[t] : 0;
    sc[t] = v;
    __syncthreads();
    for (int off = 1; off < 512; off <<= 1) {
        int add = (t >= off) ? sc[t - off] : 0;
        __syncthreads();
        sc[t] += add;
        __syncthreads();
    }
    if (t <= NBUCK) bucket_off[t] = sc[t] - v;
}

// ---------------------------------------------------------------------------
// Pass B: one block per bucket -> deg/offsets + final CSR eidx.
// ---------------------------------------------------------------------------
__global__ __launch_bounds__(1024) void kB_build(const unsigned int* __restrict__ ebuf,
                                                 const int* __restrict__ runoff,
                                                 const int* __restrict__ bucket_off,
                                                 int* __restrict__ deg,
                                                 int* __restrict__ offsets,
                                                 int* __restrict__ eidx) {
    __shared__ int runbase[SBLK + 1];
    __shared__ int runstart[SBLK];
    __shared__ int sc[256];
    __shared__ int cnt[256];
    __shared__ int off[256];
    __shared__ unsigned int stage2[MAXB];
    __shared__ unsigned int sout[MAXB];
    const int t = threadIdx.x;
    const int b = blockIdx.x;

    int rl = 0;
    if (t < SBLK) {
        int s = runoff[t * RSTRIDE + b];
        int e = runoff[t * RSTRIDE + b + 1];
        runstart[t] = t * SCHUNK + s;
        rl = e - s;
    }
    if (t < 256) { sc[t] = (t < SBLK) ? rl : 0; cnt[t] = 0; }
    __syncthreads();
    for (int o = 1; o < 256; o <<= 1) {
        int add = (t < 256 && t >= o) ? sc[t - o] : 0;
        __syncthreads();
        if (t < 256) sc[t] += add;
        __syncthreads();
    }
    if (t < SBLK) runbase[t] = sc[t] - rl;
    if (t == 0) runbase[SBLK] = sc[255];
    __syncthreads();
    const int total = runbase[SBLK];

    for (int idx = t; idx < total; idx += 1024) {
        int lo = 0, hi = SBLK - 1;
        while (lo < hi) {
            int mid = (lo + hi + 1) >> 1;
            if (runbase[mid] <= idx) lo = mid; else hi = mid - 1;
        }
        unsigned int v = ebuf[runstart[lo] + (idx - runbase[lo])];
        stage2[idx] = v;
        atomicAdd(&cnt[v & 255u], 1);
    }
    __syncthreads();

    const int gn0 = b * 256;
    const int nn = min(256, N_NODES - gn0);
    int c = (t < 256) ? cnt[t] : 0;
    if (t < 256) sc[t] = c;
    __syncthreads();
    for (int o = 1; o < 256; o <<= 1) {
        int add = (t < 256 && t >= o) ? sc[t - o] : 0;
        __syncthreads();
        if (t < 256) sc[t] += add;
        __syncthreads();
    }
    if (t < 256) { off[t] = sc[t] - c; cnt[t] = 0; }
    if (t < nn) {
        deg[gn0 + t] = c;
        offsets[gn0 + t] = bucket_off[b] + off[t];
    }
    __syncthreads();

    for (int idx = t; idx < total; idx += 1024) {
        unsigned int v = stage2[idx];
        int node = (int)(v & 255u);
        int r = atomicAdd(&cnt[node], 1);
        sout[off[node] + r] = v >> 8;
    }
    __syncthreads();
    const int base = bucket_off[b];
    for (int idx = t; idx < total; idx += 1024)
        eidx[base + idx] = (int)sout[idx];
}

// weight prep (chunk-swizzled) + xb pad zero + h -> bf16 hb conversion
__global__ __launch_bounds__(256) void k_wprep(const float* __restrict__ W1,
                                               const float* __restrict__ W2,
                                               const float* __restrict__ h,
                                               unsigned short* __restrict__ w1t,
                                               unsigned short* __restrict__ w2t,
                                               unsigned short* __restrict__ xb,
                                               unsigned short* __restrict__ hb) {
    int id = blockIdx.x * 256 + threadIdx.x;     // 3261*256 = 834816
    if (id < 16384) {                            // n*64+k
        int n = id >> 6, k = id & 63;
        int dstp = (n << 6) + ((((k >> 3) ^ (n & 7))) << 3) + (k & 7);
        w1t[dstp] = f2bf(W1[k * 256 + n]);
    } else if (id < 32768) {
        int i2 = id - 16384;                     // d*256+k2
        int d = i2 >> 8, k2 = i2 & 255;
        int dstp = (d << 8) + ((((k2 >> 3) ^ (d & 7))) << 3) + (k2 & 7);
        w2t[dstp] = f2bf(W2[k2 * 64 + d]);
    } else if (id < 34816) {                     // zero 32 pad rows of xb
        xb[100000 * 64 + (id - 32768)] = 0;
    } else {                                     // h -> bf16, 8 elems/thread
        int i = id - 34816;                      // < 800000
        int e = i * 8;
        float4 f0 = *(const float4*)&h[e];
        float4 f1 = *(const float4*)&h[e + 4];
        uint4 o;
        o.x = (unsigned)f2bf(f0.x) | ((unsigned)f2bf(f0.y) << 16);
        o.y = (unsigned)f2bf(f0.z) | ((unsigned)f2bf(f0.w) << 16);
        o.z = (unsigned)f2bf(f1.x) | ((unsigned)f2bf(f1.y) << 16);
        o.w = (unsigned)f2bf(f1.z) | ((unsigned)f2bf(f1.w) << 16);
        *(uint4*)&hb[e] = o;
    }
}

// gather from bf16 hb: 8-lane group per node, uint4 (8 bf16) per lane.
// 256 threads = 32 nodes/block. Writes chunk-swizzled bf16 xb rows.
__global__ __launch_bounds__(256) void k_gather(const unsigned short* __restrict__ hb,
                                                const int* __restrict__ offsets,
                                                const int* __restrict__ deg,
                                                const int* __restrict__ eidx,
                                                unsigned short* __restrict__ xb) {
    const int t = threadIdx.x;
    const int lane = t & 63;
    const int c = lane & 7;                       // 16B chunk: dims c*8..c*8+7
    const int node = blockIdx.x * 32 + (t >> 3);  // 3125*32 = 100000
    const int off = offsets[node];
    const int dg  = deg[node];
    const unsigned short* hc = hb + c * 8;

    float a0 = 0.f, a1 = 0.f, a2 = 0.f, a3 = 0.f;
    float a4 = 0.f, a5 = 0.f, a6 = 0.f, a7 = 0.f;
    int j = off;
    const int end = off + dg;
    for (; j + 1 < end; j += 2) {
        int i0 = eidx[j];
        int i1 = eidx[j + 1];
        uint4 v0 = *(const uint4*)&hc[(size_t)i0 * 64];
        uint4 v1 = *(const uint4*)&hc[(size_t)i1 * 64];
        a0 += __uint_as_float(v0.x << 16); a1 += __uint_as_float(v0.x & 0xffff0000u);
        a2 += __uint_as_float(v0.y << 16); a3 += __uint_as_float(v0.y & 0xffff0000u);
        a4 += __uint_as_float(v0.z << 16); a5 += __uint_as_float(v0.z & 0xffff0000u);
        a6 += __uint_as_float(v0.w << 16); a7 += __uint_as_float(v0.w & 0xffff0000u);
        a0 += __uint_as_float(v1.x << 16); a1 += __uint_as_float(v1.x & 0xffff0000u);
        a2 += __uint_as_float(v1.y << 16); a3 += __uint_as_float(v1.y & 0xffff0000u);
        a4 += __uint_as_float(v1.z << 16); a5 += __uint_as_float(v1.z & 0xffff0000u);
        a6 += __uint_as_float(v1.w << 16); a7 += __uint_as_float(v1.w & 0xffff0000u);
    }
    if (j < end) {
        int i0 = eidx[j];
        uint4 v0 = *(const uint4*)&hc[(size_t)i0 * 64];
        a0 += __uint_as_float(v0.x << 16); a1 += __uint_as_float(v0.x & 0xffff0000u);
        a2 += __uint_as_float(v0.y << 16); a3 += __uint_as_float(v0.y & 0xffff0000u);
        a4 += __uint_as_float(v0.z << 16); a5 += __uint_as_float(v0.z & 0xffff0000u);
        a6 += __uint_as_float(v0.w << 16); a7 += __uint_as_float(v0.w & 0xffff0000u);
    }
    const float inv = 1.0f / (float)max(dg, 1);
    uint4 ov = *(const uint4*)&hc[(size_t)node * 64];
    float x0 = fmaf(a0, inv, __uint_as_float(ov.x << 16));
    float x1 = fmaf(a1, inv, __uint_as_float(ov.x & 0xffff0000u));
    float x2 = fmaf(a2, inv, __uint_as_float(ov.y << 16));
    float x3 = fmaf(a3, inv, __uint_as_float(ov.y & 0xffff0000u));
    float x4 = fmaf(a4, inv, __uint_as_float(ov.z << 16));
    float x5 = fmaf(a5, inv, __uint_as_float(ov.z & 0xffff0000u));
    float x6 = fmaf(a6, inv, __uint_as_float(ov.w << 16));
    float x7 = fmaf(a7, inv, __uint_as_float(ov.w & 0xffff0000u));
    uint4 o;
    o.x = (unsigned)f2bf(x0) | ((unsigned)f2bf(x1) << 16);
    o.y = (unsigned)f2bf(x2) | ((unsigned)f2bf(x3) << 16);
    o.z = (unsigned)f2bf(x4) | ((unsigned)f2bf(x5) << 16);
    o.w = (unsigned)f2bf(x6) | ((unsigned)f2bf(x7) << 16);
    *(uint4*)&xb[(size_t)node * 64 + ((c ^ (node & 7)) << 3)] = o;
}

// ---------------------------------------------------------------------------
// Fused MLP core (unchanged from round 2)
// ---------------------------------------------------------------------------
__device__ __forceinline__ void mlp_tile(const unsigned short* sXw,
                                         const unsigned short* sW1,
                                         const unsigned short* sW2,
                                         unsigned short* sHw,
                                         const float* sB1,
                                         int l15, int g4, int s7,
                                         f32x4 oacc[4]) {
    bf16x8 xf0 = *(const bf16x8*)&sXw[l15 * 64 + ((g4 ^ s7) << 3)];
    bf16x8 xf1 = *(const bf16x8*)&sXw[l15 * 64 + (((g4 + 4) ^ s7) << 3)];
#pragma unroll
    for (int dt = 0; dt < 4; ++dt) oacc[dt] = (f32x4){0.f, 0.f, 0.f, 0.f};

#pragma unroll
    for (int p = 0; p < 4; ++p) {
#pragma unroll
        for (int nt2 = 0; nt2 < 4; ++nt2) {
            const int n0 = p * 64 + nt2 * 16;
            f32x4 hacc = (f32x4){0.f, 0.f, 0.f, 0.f};
            bf16x8 wf0 = *(const bf16x8*)&sW1[(n0 + l15) * 64 + ((g4 ^ s7) << 3)];
            bf16x8 wf1 = *(const bf16x8*)&sW1[(n0 + l15) * 64 + (((g4 + 4) ^ s7) << 3)];
            hacc = __builtin_amdgcn_mfma_f32_16x16x32_bf16(wf0, xf0, hacc, 0, 0, 0);
            hacc = __builtin_amdgcn_mfma_f32_16x16x32_bf16(wf1, xf1, hacc, 0, 0, 0);
            float4 bq = *(const float4*)&sB1[n0 + g4 * 4];
            ushort4 pk;
            pk.x = f2bf(fmaxf(hacc[0] + bq.x, 0.f));
            pk.y = f2bf(fmaxf(hacc[1] + bq.y, 0.f));
            pk.z = f2bf(fmaxf(hacc[2] + bq.z, 0.f));
            pk.w = f2bf(fmaxf(hacc[3] + bq.w, 0.f));
            int qh = nt2 * 2 + (g4 >> 1);
            *(ushort4*)&sHw[l15 * 64 + ((qh ^ s7) << 3) + ((g4 & 1) << 2)] = pk;
        }
#pragma unroll
        for (int s2 = 0; s2 < 2; ++s2) {
            bf16x8 a2 = *(const bf16x8*)&sHw[l15 * 64 + (((s2 * 4 + g4) ^ s7) << 3)];
#pragma unroll
            for (int dt = 0; dt < 4; ++dt) {
                int q = p * 8 + s2 * 4 + g4;
                bf16x8 w2f = *(const bf16x8*)&sW2[(dt * 16 + l15) * 256 + ((q ^ s7) << 3)];
                oacc[dt] = __builtin_amdgcn_mfma_f32_16x16x32_bf16(a2, w2f, oacc[dt], 0, 0, 0);
            }
        }
    }
}

// single-pass MLP + BN: pass1 MFMA keeping post-relu vals in regs + stats,
// software grid barrier (all 256 blocks co-resident: 113KB LDS -> 1 blk/CU),
// then BN finalize + streamed output stores.
__global__ __launch_bounds__(512, 2) void k_mlpf(const unsigned short* __restrict__ xb,
                                                 const unsigned short* __restrict__ w1t,
                                                 const unsigned short* __restrict__ w2t,
                                                 const float* __restrict__ b1,
                                                 const float* __restrict__ b2,
                                                 const float* __restrict__ gamma,
                                                 const float* __restrict__ beta,
                                                 float* __restrict__ stats,
                                                 int* __restrict__ bar,
                                                 float* __restrict__ out,
                                                 float* __restrict__ dump) {
    __shared__ unsigned short sW1[256 * 64];
    __shared__ unsigned short sW2[64 * 256];
    __shared__ unsigned short sH[8][16 * 64];
    __shared__ unsigned short sX[8][2][16 * 64];
    __shared__ float sB1[256];
    const int t = threadIdx.x;
    const int lane = t & 63;
    const int w = t >> 6;
    const int l15 = lane & 15;
    const int g4 = lane >> 4;
    const int s7 = l15 & 7;
    const int bid = blockIdx.x;

    for (int i = t; i < 2048; i += 512)
        *(uint4*)&sW1[i * 8] = *(const uint4*)&w1t[i * 8];
    for (int i = t; i < 2048; i += 512)
        *(uint4*)&sW2[i * 8] = *(const uint4*)&w2t[i * 8];
    if (t < 256) sB1[t] = b1[t];
    __syncthreads();

    float b2v[4];
#pragma unroll
    for (int dt = 0; dt < 4; ++dt) b2v[dt] = b2[dt * 16 + l15];

    float lsum[4] = {0.f, 0.f, 0.f, 0.f};
    float lsq[4]  = {0.f, 0.f, 0.f, 0.f};
    f32x4 osave[MAXIT][4];

    int cur = 0;
    {
        int r0 = min(bid * 128 + w * 16, XBROWS - 16);
        stage_issue(xb + (size_t)r0 * 64 + lane * 8, &sX[w][0][0]);
    }
#pragma unroll
    for (int it = 0; it < MAXIT; ++it) {
        int gp = bid + it * MLPGRID;
        int gpn = gp + MLPGRID; if (gpn >= NGP) gpn = gp;
        int r0n = min(gpn * 128 + w * 16, XBROWS - 16);
        stage_issue(xb + (size_t)r0n * 64 + lane * 8, &sX[w][cur ^ 1][0]);
        WAITV(2);
        __builtin_amdgcn_sched_barrier(0);
        const int row0 = gp * 128 + w * 16;
        if (gp < NGP && row0 < XBROWS) {
            f32x4 oacc[4];
            mlp_tile(&sX[w][cur][0], sW1, sW2, &sH[w][0], sB1, l15, g4, s7, oacc);
#pragma unroll
            for (int dt = 0; dt < 4; ++dt) {
#pragma unroll
                for (int r = 0; r < 4; ++r) {
                    float val = fmaxf(oacc[dt][r] + b2v[dt], 0.f);
                    osave[it][dt][r] = val;
                    int mabs = row0 + g4 * 4 + r;
                    if (mabs < N_NODES) {
                        lsum[dt] += val;
                        lsq[dt] += val * val;
                    }
                }
            }
        }
        cur ^= 1;
    }

    // block-level stats reduction (reuse sW1 memory)
    __syncthreads();
    float* sred = (float*)&sW1[0];                // [512][8] = 16 KB
#pragma unroll
    for (int dt = 0; dt < 4; ++dt) {
        sred[t * 8 + dt] = lsum[dt];
        sred[t * 8 + 4 + dt] = lsq[dt];
    }
    __syncthreads();
    if (t < 128) {
        int issq = (t >= 64) ? 4 : 0;
        int d = t & 63;
        int dt = d >> 4, dl = d & 15;
        float acc = 0.f;
        for (int i = 0; i < 32; ++i) acc += sred[(dl + 16 * i) * 8 + issq + dt];
        atomicAdd(&stats[(issq ? 64 : 0) + d], acc);
    }

    // software grid barrier (all blocks co-resident by construction)
    __syncthreads();
    if (t == 0) {
        __hip_atomic_fetch_add(bar, 1, __ATOMIC_ACQ_REL, __HIP_MEMORY_SCOPE_AGENT);
        while (__hip_atomic_load(bar, __ATOMIC_ACQUIRE, __HIP_MEMORY_SCOPE_AGENT)
               < MLPGRID)
            __builtin_amdgcn_s_sleep(4);
    }
    __syncthreads();

    // BN coefficients per lane (coherent reads via device-scope atomic loads)
    float scv[4], shv[4];
    const float inv_n = 1.0f / (float)N_NODES;
#pragma unroll
    for (int dt = 0; dt < 4; ++dt) {
        int d = dt * 16 + l15;
        float sm = __hip_atomic_load(&stats[d], __ATOMIC_RELAXED,
                                     __HIP_MEMORY_SCOPE_AGENT);
        float sq = __hip_atomic_load(&stats[64 + d], __ATOMIC_RELAXED,
                                     __HIP_MEMORY_SCOPE_AGENT);
        float m = sm * inv_n;
        float v = sq * inv_n - m * m;
        float sc = gamma[d] * rsqrtf(v + BN_EPS);
        scv[dt] = sc;
        shv[dt] = beta[d] - m * sc;
    }

    // epilogue: BN apply from registers, bounce through sH, streamed stores
#pragma unroll
    for (int it = 0; it < MAXIT; ++it) {
        int gp = bid + it * MLPGRID;
        const int row0 = gp * 128 + w * 16;
        if (gp >= NGP || row0 >= XBROWS) continue;
        float* sHf = (float*)&sH[w][0];           // [8][64] f32 = 2048 B
#pragma unroll
        for (int hh = 0; hh < 2; ++hh) {
            asm volatile("" ::: "memory");
            if ((g4 >> 1) == hh) {
#pragma unroll
                for (int dt = 0; dt < 4; ++dt) {
#pragma unroll
                    for (int r = 0; r < 4; ++r) {
                        float val = fmaf(osave[it][dt][r], scv[dt], shv[dt]);
                        sHf[((g4 & 1) * 4 + r) * 64 + dt * 16 + l15] = val;
                    }
                }
            }
            asm volatile("" ::: "memory");
#pragma unroll
            for (int j = 0; j < 2; ++j) {
                int rl = j * 4 + (lane >> 4);
                int rg = row0 + hh * 8 + rl;
                float4 v = *(const float4*)&sHf[rl * 64 + (lane & 15) * 4];
                float* dstp = (rg < N_NODES)
                    ? &out[(size_t)rg * 64 + (lane & 15) * 4]
                    : &dump[lane * 4];
                *(float4*)dstp = v;
            }
        }
    }
}

extern "C" void kernel_launch(void* const* d_in, const int* in_sizes, int n_in,
                              void* d_out, int out_size, void* d_ws, size_t ws_size,
                              hipStream_t stream) {
    const float* h     = (const float*)d_in[0];
    const float* W1    = (const float*)d_in[1];
    const float* b1    = (const float*)d_in[2];
    const float* W2    = (const float*)d_in[3];
    const float* b2    = (const float*)d_in[4];
    const float* gamma = (const float*)d_in[5];
    const float* beta  = (const float*)d_in[6];
    const int*   src   = (const int*)d_in[7];
    const int*   dst   = (const int*)d_in[8];

    int* wsi = (int*)d_ws;
    int*            deg        = wsi;                              // 100000
    float*          stats      = (float*)(wsi + 100000);           // 128
    int*            bar        = wsi + 100128;                     // 128
    int*            bucket_cnt = wsi + 100256;                     // 400
    int*            bucket_off = wsi + 100656;                     // 400
    int*            offsets    = wsi + 101056;                     // 100000
    int*            runoff     = wsi + 201056;                     // 76832
    float*          dump       = (float*)(wsi + 201056);           // reuse (dead)
    unsigned short* w1t        = (unsigned short*)(wsi + 277888);  // 8192 ints
    unsigned short* w2t        = (unsigned short*)(wsi + 286080);  // 8192 ints
    int*            eidx       = wsi + 294272;                     // 1600000
    unsigned short* xb         = (unsigned short*)(wsi + 1894272); // 3201024 ints
    unsigned int*   ebuf       = (unsigned int*)(wsi + 1894272);   // aliases xb head
    unsigned short* hb         = (unsigned short*)(wsi + 5095296); // 3200000 ints
    float*          out        = (float*)d_out;

    // zero stats + bar + bucket_cnt (contiguous: 2624 B)
    hipMemsetAsync(wsi + 100000, 0, 2624, stream);

    kA_scatter<<<SBLK, 1024, 0, stream>>>(src, dst, ebuf, runoff, bucket_cnt);
    kA_scan<<<1, 512, 0, stream>>>(bucket_cnt, bucket_off);
    kB_build<<<NBUCK, 1024, 0, stream>>>(ebuf, runoff, bucket_off, deg, offsets, eidx);
    k_wprep<<<3261, 256, 0, stream>>>(W1, W2, h, w1t, w2t, xb, hb);
    k_gather<<<3125, 256, 0, stream>>>(hb, offsets, deg, eidx, xb);
    k_mlpf<<<MLPGRID, 512, 0, stream>>>(xb, w1t, w2t, b1, b2, gamma, beta,
                                        stats, bar, out, dump);
}